// Round 2
// baseline (545.425 us; speedup 1.0000x reference)
//
#include <hip/hip_runtime.h>
#include <hip/hip_bf16.h>

#define NNODES 100000
#define NEDGES 1600000
#define ALPHA  0.2f
#define EPSV   1e-9f

typedef __bf16 bf16x8 __attribute__((ext_vector_type(8)));
typedef float  f32x4  __attribute__((ext_vector_type(4)));
typedef unsigned short u16x8 __attribute__((ext_vector_type(8)));

// manual RNE f32 -> bf16 bits
static __device__ inline unsigned short f2bf(float f) {
    unsigned int u = __float_as_uint(f);
    unsigned int r = u + 0x7fff + ((u >> 16) & 1);
    return (unsigned short)(r >> 16);
}
static __device__ inline float bf2f(unsigned short v) {
    return __uint_as_float((unsigned int)v << 16);
}

// ---------------- zero counts ----------------
__global__ void k_zero(int* __restrict__ p, int n) {
    int i = blockIdx.x * blockDim.x + threadIdx.x;
    if (i < n) p[i] = 0;
}

// ---------------- W [256][256] f32 -> Wt [n][k] bf16 (transposed) ----------------
__global__ void k_prepw(const float* __restrict__ W, unsigned short* __restrict__ Wt) {
    const int i = blockIdx.x * 256 + threadIdx.x;  // i = n*256 + k
    const int n = i >> 8, k = i & 255;
    Wt[i] = f2bf(W[k * 256 + n]);
}

// ---------------- bf16 MFMA GEMM: Wh[bf16] = h @ W (round-0, unchanged) ----------------
#define BM 128
#define BK 32
#define LSTRIDE 40
__global__ __launch_bounds__(256, 2) void k_gemm(const float* __restrict__ h,
                                                 const unsigned short* __restrict__ Wt,
                                                 unsigned short* __restrict__ Wh) {
    __shared__ __align__(16) unsigned short As[BM * LSTRIDE];
    __shared__ __align__(16) unsigned short Bs[256 * LSTRIDE];
    const int tid  = threadIdx.x;
    const int m0   = blockIdx.x * BM;
    const int wave = tid >> 6;
    const int lane = tid & 63;
    const int wm = (wave & 1) * 64;
    const int wn = (wave >> 1) * 128;
    const int fm = lane & 15;
    const int fq = lane >> 4;
    const int fk = fq * 8;

    f32x4 acc[4][8];
    const f32x4 z = {0.f, 0.f, 0.f, 0.f};
#pragma unroll
    for (int i = 0; i < 4; ++i)
#pragma unroll
        for (int j = 0; j < 8; ++j) acc[i][j] = z;

    const int arow = tid >> 1;
    const int acol = (tid & 1) * 16;
    const bool arow_ok = (m0 + arow) < NNODES;
    const float* hrow = h + (size_t)(m0 + arow) * 256 + acol;

    for (int kc = 0; kc < 256; kc += BK) {
        float4 a0, a1, a2, a3;
        if (arow_ok) {
            a0 = *(const float4*)(hrow + kc + 0);
            a1 = *(const float4*)(hrow + kc + 4);
            a2 = *(const float4*)(hrow + kc + 8);
            a3 = *(const float4*)(hrow + kc + 12);
        } else {
            a0 = a1 = a2 = a3 = make_float4(0.f, 0.f, 0.f, 0.f);
        }
        u16x8 bv[4];
#pragma unroll
        for (int q = 0; q < 4; ++q) {
            const int c = tid + 256 * q;
            const int n = c >> 2, koff = (c & 3) * 8;
            bv[q] = *(const u16x8*)(Wt + n * 256 + kc + koff);
        }
        __syncthreads();
        u16x8 p0, p1;
        p0[0]=f2bf(a0.x); p0[1]=f2bf(a0.y); p0[2]=f2bf(a0.z); p0[3]=f2bf(a0.w);
        p0[4]=f2bf(a1.x); p0[5]=f2bf(a1.y); p0[6]=f2bf(a1.z); p0[7]=f2bf(a1.w);
        p1[0]=f2bf(a2.x); p1[1]=f2bf(a2.y); p1[2]=f2bf(a2.z); p1[3]=f2bf(a2.w);
        p1[4]=f2bf(a3.x); p1[5]=f2bf(a3.y); p1[6]=f2bf(a3.z); p1[7]=f2bf(a3.w);
        *(u16x8*)&As[arow * LSTRIDE + acol]     = p0;
        *(u16x8*)&As[arow * LSTRIDE + acol + 8] = p1;
#pragma unroll
        for (int q = 0; q < 4; ++q) {
            const int c = tid + 256 * q;
            const int n = c >> 2, koff = (c & 3) * 8;
            *(u16x8*)&Bs[n * LSTRIDE + koff] = bv[q];
        }
        __syncthreads();
        bf16x8 af[4], bfr[8];
#pragma unroll
        for (int i = 0; i < 4; ++i)
            af[i] = __builtin_bit_cast(bf16x8,
                *(const u16x8*)&As[(wm + 16 * i + fm) * LSTRIDE + fk]);
#pragma unroll
        for (int j = 0; j < 8; ++j)
            bfr[j] = __builtin_bit_cast(bf16x8,
                *(const u16x8*)&Bs[(wn + 16 * j + fm) * LSTRIDE + fk]);
#pragma unroll
        for (int i = 0; i < 4; ++i)
#pragma unroll
            for (int j = 0; j < 8; ++j)
                acc[i][j] = __builtin_amdgcn_mfma_f32_16x16x32_bf16(af[i], bfr[j], acc[i][j], 0, 0, 0);
    }
#pragma unroll
    for (int i = 0; i < 4; ++i) {
#pragma unroll
        for (int r = 0; r < 4; ++r) {
            const int grow = m0 + wm + 16 * i + fq * 4 + r;
            if (grow < NNODES) {
                unsigned short* orow = Wh + (size_t)grow * 256 + wn + fm;
#pragma unroll
                for (int j = 0; j < 8; ++j)
                    orow[16 * j] = f2bf(acc[i][j][r]);
            }
        }
    }
}

// ---------------- count out-degree of src (CSR build) ----------------
__global__ __launch_bounds__(256) void k_count(const int* __restrict__ src,
                                               int* __restrict__ counts) {
    const int e = blockIdx.x * 256 + threadIdx.x;
    if (e < NEDGES) atomicAdd(&counts[src[e]], 1);
}

// ---------------- exclusive scan of counts -> row_start ----------------
__global__ __launch_bounds__(256) void k_scan1(const int* __restrict__ counts,
                                               int* __restrict__ row_start,
                                               int* __restrict__ blockSums) {
    __shared__ int ssum[256];
    const int tid = threadIdx.x;
    const int base = blockIdx.x * 1024 + tid * 4;
    int v[4];
#pragma unroll
    for (int c = 0; c < 4; ++c) v[c] = (base + c < NNODES) ? counts[base + c] : 0;
    const int s = v[0] + v[1] + v[2] + v[3];
    ssum[tid] = s;
    __syncthreads();
    for (int off = 1; off < 256; off <<= 1) {
        const int t = (tid >= off) ? ssum[tid - off] : 0;
        __syncthreads();
        ssum[tid] += t;
        __syncthreads();
    }
    if (tid == 255) blockSums[blockIdx.x] = ssum[255];
    int p = ssum[tid] - s;
#pragma unroll
    for (int c = 0; c < 4; ++c) {
        if (base + c < NNODES) row_start[base + c] = p;
        p += v[c];
    }
}

__global__ __launch_bounds__(256) void k_scan2(int* __restrict__ blockSums, int nb) {
    __shared__ int ssum[256];
    const int tid = threadIdx.x;
    const int s = (tid < nb) ? blockSums[tid] : 0;
    ssum[tid] = s;
    __syncthreads();
    for (int off = 1; off < 256; off <<= 1) {
        const int t = (tid >= off) ? ssum[tid - off] : 0;
        __syncthreads();
        ssum[tid] += t;
        __syncthreads();
    }
    if (tid < nb) blockSums[tid] = ssum[tid] - s;
}

// add block offsets; also initialize the scatter cursor
__global__ void k_scan3(int* __restrict__ row_start,
                        int* __restrict__ cursor,
                        const int* __restrict__ blockSums) {
    const int i = blockIdx.x * blockDim.x + threadIdx.x;
    if (i < NNODES) {
        const int v = row_start[i] + blockSums[i >> 10];
        row_start[i] = v;
        cursor[i] = v;
    }
}

// ---------------- scatter dst into CSR order (full-wave independent stores) -------
__global__ __launch_bounds__(256) void k_scatter(const int* __restrict__ src,
                                                 const int* __restrict__ dst,
                                                 int* __restrict__ cursor,
                                                 int* __restrict__ sorted_dst) {
    const int e = blockIdx.x * 256 + threadIdx.x;
    if (e >= NEDGES) return;
    const int pos = atomicAdd(&cursor[src[e]], 1);
    sorted_dst[pos] = dst[e];
}

// ---------------- fused attention + aggregation ----------------
// 32 lanes per node. Lane layout: sub = lane&31; channel-owner role: lane owns
// Wh/out channels [sub*8, sub*8+8). Label role: group g = sub>>3 handles edge g
// of each 4-edge batch; lane holds label channels [(sub&7)*4, +4).
// Per 4-edge batch: gather label[dst_g] (float4/lane), dot via 3x shfl_xor within
// the 8-lane group, leakyrelu+exp, broadcast 4 w's, then FMA the 4 Wh rows.
__global__ __launch_bounds__(256) void k_aggregate(const unsigned short* __restrict__ Wh,
                                                   const float* __restrict__ label,
                                                   const int* __restrict__ row_start,
                                                   const int* __restrict__ sorted_dst,
                                                   float* __restrict__ out) {
    const int node = blockIdx.x * 8 + (threadIdx.x >> 5);
    if (node >= NNODES) return;
    const int lane = threadIdx.x & 63;
    const int sub  = lane & 31;
    const int base32 = lane & 32;         // my half's lane offset within the wave
    const int g  = sub >> 3;              // 4-edge-batch group id
    const int c4 = (sub & 7) * 4;         // label channel base
    const int rs = row_start[node];
    const int re = (node == NNODES - 1) ? NEDGES : row_start[node + 1];
    const unsigned short* __restrict__ Whc = Wh + sub * 8;

    const float4 lsv = *(const float4*)&label[(size_t)node * 32 + c4];

    float acc[8] = {0.f, 0.f, 0.f, 0.f, 0.f, 0.f, 0.f, 0.f};
    float wsum = 0.f;
    int i = rs;
    for (; i + 4 <= re; i += 4) {
        const int d0 = sorted_dst[i + 0];
        const int d1 = sorted_dst[i + 1];
        const int d2 = sorted_dst[i + 2];
        const int d3 = sorted_dst[i + 3];
        const int dm = (g & 2) ? ((g & 1) ? d3 : d2) : ((g & 1) ? d1 : d0);
        const float4 ldv = *(const float4*)&label[(size_t)dm * 32 + c4];
        const u16x8 v0 = *(const u16x8*)&Whc[(size_t)d0 * 256];
        const u16x8 v1 = *(const u16x8*)&Whc[(size_t)d1 * 256];
        const u16x8 v2 = *(const u16x8*)&Whc[(size_t)d2 * 256];
        const u16x8 v3 = *(const u16x8*)&Whc[(size_t)d3 * 256];
        float p = lsv.x * ldv.x + lsv.y * ldv.y + lsv.z * ldv.z + lsv.w * ldv.w;
        p += __shfl_xor(p, 1);
        p += __shfl_xor(p, 2);
        p += __shfl_xor(p, 4);            // all 8 lanes of group g now hold dot_g
        const float lr = fmaxf(p, ALPHA * p);
        const float wv = expf(lr);
        const float w0 = __shfl(wv, base32 + 0);
        const float w1 = __shfl(wv, base32 + 8);
        const float w2 = __shfl(wv, base32 + 16);
        const float w3 = __shfl(wv, base32 + 24);
        wsum += (w0 + w1) + (w2 + w3);
#pragma unroll
        for (int c = 0; c < 8; ++c) {
            acc[c] = fmaf(w0, bf2f(v0[c]), acc[c]);
            acc[c] = fmaf(w1, bf2f(v1[c]), acc[c]);
            acc[c] = fmaf(w2, bf2f(v2[c]), acc[c]);
            acc[c] = fmaf(w3, bf2f(v3[c]), acc[c]);
        }
    }
    for (; i < re; ++i) {
        // single edge: all 4 groups redundantly compute the same dot
        const int d = sorted_dst[i];
        const float4 ldv = *(const float4*)&label[(size_t)d * 32 + c4];
        const u16x8 v = *(const u16x8*)&Whc[(size_t)d * 256];
        float p = lsv.x * ldv.x + lsv.y * ldv.y + lsv.z * ldv.z + lsv.w * ldv.w;
        p += __shfl_xor(p, 1);
        p += __shfl_xor(p, 2);
        p += __shfl_xor(p, 4);            // every lane holds the full dot
        const float lr = fmaxf(p, ALPHA * p);
        const float w = expf(lr);
        wsum += w;
#pragma unroll
        for (int c = 0; c < 8; ++c) acc[c] = fmaf(w, bf2f(v[c]), acc[c]);
    }
    const float inv = 1.f / fmaxf(wsum, EPSV);
    float4 o0 = make_float4(acc[0] * inv, acc[1] * inv, acc[2] * inv, acc[3] * inv);
    float4 o1 = make_float4(acc[4] * inv, acc[5] * inv, acc[6] * inv, acc[7] * inv);
    float* orow = out + (size_t)node * 256 + sub * 8;
    *(float4*)(orow + 0) = o0;
    *(float4*)(orow + 4) = o1;
}

extern "C" void kernel_launch(void* const* d_in, const int* in_sizes, int n_in,
                              void* d_out, int out_size, void* d_ws, size_t ws_size,
                              hipStream_t stream) {
    const float* h     = (const float*)d_in[0];   // [N,256]
    const float* label = (const float*)d_in[1];   // [N,32]
    const float* W     = (const float*)d_in[2];   // [256,256]
    const int*   adj   = (const int*)d_in[3];     // [2,E]
    const int* src = adj;
    const int* dst = adj + NEDGES;
    float* out = (float*)d_out;

    // workspace layout (bytes, 16B-aligned offsets)
    char* ws = (char*)d_ws;
    unsigned short* Wh  = (unsigned short*)(ws + 0);          // N*256*2 = 51,200,000
    unsigned short* Wt  = (unsigned short*)(ws + 51200000);   // 256*256*2 = 131,072
    int* sorted_dst     = (int*)  (ws + 51400000);            // E*4 = 6,400,000
    int* counts         = (int*)  (ws + 57800000);            // N*4
    int* row_start      = (int*)  (ws + 58200000);            // N*4
    int* cursor         = (int*)  (ws + 58600000);            // N*4
    int* blockSums      = (int*)  (ws + 59000000);            // 1024*4

    k_zero<<<(NNODES + 255) / 256, 256, 0, stream>>>(counts, NNODES);
    k_prepw<<<256, 256, 0, stream>>>(W, Wt);
    k_gemm<<<(NNODES + BM - 1) / BM, 256, 0, stream>>>(h, Wt, Wh);
    k_count<<<(NEDGES + 255) / 256, 256, 0, stream>>>(src, counts);

    const int nb = (NNODES + 1023) / 1024;  // 98
    k_scan1<<<nb, 256, 0, stream>>>(counts, row_start, blockSums);
    k_scan2<<<1, 256, 0, stream>>>(blockSums, nb);
    k_scan3<<<(NNODES + 255) / 256, 256, 0, stream>>>(row_start, cursor, blockSums);

    k_scatter<<<(NEDGES + 255) / 256, 256, 0, stream>>>(src, dst, cursor, sorted_dst);
    k_aggregate<<<(NNODES + 7) / 8, 256, 0, stream>>>(Wh, label, row_start, sorted_dst, out);
}

// Round 3
// 456.658 us; speedup vs baseline: 1.1944x; 1.1944x over previous
//
#include <hip/hip_runtime.h>
#include <hip/hip_bf16.h>

#define NNODES 100000
#define NEDGES 1600000
#define ALPHA  0.2f
#define EPSV   1e-9f

typedef __bf16 bf16x8 __attribute__((ext_vector_type(8)));
typedef float  f32x4  __attribute__((ext_vector_type(4)));
typedef unsigned short u16x8 __attribute__((ext_vector_type(8)));

// manual RNE f32 -> bf16 bits
static __device__ inline unsigned short f2bf(float f) {
    unsigned int u = __float_as_uint(f);
    unsigned int r = u + 0x7fff + ((u >> 16) & 1);
    return (unsigned short)(r >> 16);
}
static __device__ inline float bf2f(unsigned short v) {
    return __uint_as_float((unsigned int)v << 16);
}

// ---------------- init: zero counts + W [256][256] f32 -> Wt bf16 (transposed) ----
__global__ void k_init(const float* __restrict__ W, unsigned short* __restrict__ Wt,
                       int* __restrict__ counts) {
    const int i = blockIdx.x * 256 + threadIdx.x;
    if (i < NNODES) counts[i] = 0;
    if (i < 65536) {
        const int n = i >> 8, k = i & 255;
        Wt[i] = f2bf(W[k * 256 + n]);
    }
}

// ---------------- bf16 MFMA GEMM: Wh = h @ W, with fused edge-count prologue -------
// Counting atomics are fired before the MFMA loop; they drain asynchronously
// under the compute-bound GEMM body (one atomic pass total for the whole pipeline).
#define BM 128
#define BK 32
#define LSTRIDE 40
__global__ __launch_bounds__(256, 2) void k_gemm(const float* __restrict__ h,
                                                 const unsigned short* __restrict__ Wt,
                                                 unsigned short* __restrict__ Wh,
                                                 const int* __restrict__ src,
                                                 int* __restrict__ counts,
                                                 int* __restrict__ pos_in_row) {
    const int tid  = threadIdx.x;

    // --- fused count/position pass: 2048 edges per block ---
    {
        const int ebase = blockIdx.x * 2048 + tid;
#pragma unroll
        for (int q = 0; q < 8; ++q) {
            const int e = ebase + q * 256;
            if (e < NEDGES) pos_in_row[e] = atomicAdd(&counts[src[e]], 1);
        }
    }

    __shared__ __align__(16) unsigned short As[BM * LSTRIDE];
    __shared__ __align__(16) unsigned short Bs[256 * LSTRIDE];
    const int m0   = blockIdx.x * BM;
    const int wave = tid >> 6;
    const int lane = tid & 63;
    const int wm = (wave & 1) * 64;
    const int wn = (wave >> 1) * 128;
    const int fm = lane & 15;
    const int fq = lane >> 4;
    const int fk = fq * 8;

    f32x4 acc[4][8];
    const f32x4 z = {0.f, 0.f, 0.f, 0.f};
#pragma unroll
    for (int i = 0; i < 4; ++i)
#pragma unroll
        for (int j = 0; j < 8; ++j) acc[i][j] = z;

    const int arow = tid >> 1;
    const int acol = (tid & 1) * 16;
    const bool arow_ok = (m0 + arow) < NNODES;
    const float* hrow = h + (size_t)(m0 + arow) * 256 + acol;

    for (int kc = 0; kc < 256; kc += BK) {
        float4 a0, a1, a2, a3;
        if (arow_ok) {
            a0 = *(const float4*)(hrow + kc + 0);
            a1 = *(const float4*)(hrow + kc + 4);
            a2 = *(const float4*)(hrow + kc + 8);
            a3 = *(const float4*)(hrow + kc + 12);
        } else {
            a0 = a1 = a2 = a3 = make_float4(0.f, 0.f, 0.f, 0.f);
        }
        u16x8 bv[4];
#pragma unroll
        for (int q = 0; q < 4; ++q) {
            const int c = tid + 256 * q;
            const int n = c >> 2, koff = (c & 3) * 8;
            bv[q] = *(const u16x8*)(Wt + n * 256 + kc + koff);
        }
        __syncthreads();
        u16x8 p0, p1;
        p0[0]=f2bf(a0.x); p0[1]=f2bf(a0.y); p0[2]=f2bf(a0.z); p0[3]=f2bf(a0.w);
        p0[4]=f2bf(a1.x); p0[5]=f2bf(a1.y); p0[6]=f2bf(a1.z); p0[7]=f2bf(a1.w);
        p1[0]=f2bf(a2.x); p1[1]=f2bf(a2.y); p1[2]=f2bf(a2.z); p1[3]=f2bf(a2.w);
        p1[4]=f2bf(a3.x); p1[5]=f2bf(a3.y); p1[6]=f2bf(a3.z); p1[7]=f2bf(a3.w);
        *(u16x8*)&As[arow * LSTRIDE + acol]     = p0;
        *(u16x8*)&As[arow * LSTRIDE + acol + 8] = p1;
#pragma unroll
        for (int q = 0; q < 4; ++q) {
            const int c = tid + 256 * q;
            const int n = c >> 2, koff = (c & 3) * 8;
            *(u16x8*)&Bs[n * LSTRIDE + koff] = bv[q];
        }
        __syncthreads();
        bf16x8 af[4], bfr[8];
#pragma unroll
        for (int i = 0; i < 4; ++i)
            af[i] = __builtin_bit_cast(bf16x8,
                *(const u16x8*)&As[(wm + 16 * i + fm) * LSTRIDE + fk]);
#pragma unroll
        for (int j = 0; j < 8; ++j)
            bfr[j] = __builtin_bit_cast(bf16x8,
                *(const u16x8*)&Bs[(wn + 16 * j + fm) * LSTRIDE + fk]);
#pragma unroll
        for (int i = 0; i < 4; ++i)
#pragma unroll
            for (int j = 0; j < 8; ++j)
                acc[i][j] = __builtin_amdgcn_mfma_f32_16x16x32_bf16(af[i], bfr[j], acc[i][j], 0, 0, 0);
    }
#pragma unroll
    for (int i = 0; i < 4; ++i) {
#pragma unroll
        for (int r = 0; r < 4; ++r) {
            const int grow = m0 + wm + 16 * i + fq * 4 + r;
            if (grow < NNODES) {
                unsigned short* orow = Wh + (size_t)grow * 256 + wn + fm;
#pragma unroll
                for (int j = 0; j < 8; ++j)
                    orow[16 * j] = f2bf(acc[i][j][r]);
            }
        }
    }
}

// ---------------- exclusive scan of counts -> row_start ----------------
__global__ __launch_bounds__(256) void k_scan1(const int* __restrict__ counts,
                                               int* __restrict__ row_start,
                                               int* __restrict__ blockSums) {
    __shared__ int ssum[256];
    const int tid = threadIdx.x;
    const int base = blockIdx.x * 1024 + tid * 4;
    int v[4];
#pragma unroll
    for (int c = 0; c < 4; ++c) v[c] = (base + c < NNODES) ? counts[base + c] : 0;
    const int s = v[0] + v[1] + v[2] + v[3];
    ssum[tid] = s;
    __syncthreads();
    for (int off = 1; off < 256; off <<= 1) {
        const int t = (tid >= off) ? ssum[tid - off] : 0;
        __syncthreads();
        ssum[tid] += t;
        __syncthreads();
    }
    if (tid == 255) blockSums[blockIdx.x] = ssum[255];
    int p = ssum[tid] - s;
#pragma unroll
    for (int c = 0; c < 4; ++c) {
        if (base + c < NNODES) row_start[base + c] = p;
        p += v[c];
    }
}

__global__ __launch_bounds__(256) void k_scan2(int* __restrict__ blockSums, int nb) {
    __shared__ int ssum[256];
    const int tid = threadIdx.x;
    const int s = (tid < nb) ? blockSums[tid] : 0;
    ssum[tid] = s;
    __syncthreads();
    for (int off = 1; off < 256; off <<= 1) {
        const int t = (tid >= off) ? ssum[tid - off] : 0;
        __syncthreads();
        ssum[tid] += t;
        __syncthreads();
    }
    if (tid < nb) blockSums[tid] = ssum[tid] - s;
}

__global__ void k_scan3(int* __restrict__ row_start, const int* __restrict__ blockSums) {
    const int i = blockIdx.x * blockDim.x + threadIdx.x;
    if (i < NNODES) row_start[i] += blockSums[i >> 10];
}

// ---------------- scatter dst into CSR order (no atomics, independent stores) -----
__global__ __launch_bounds__(256) void k_scatter(const int* __restrict__ src,
                                                 const int* __restrict__ dst,
                                                 const int* __restrict__ pos_in_row,
                                                 const int* __restrict__ row_start,
                                                 int* __restrict__ sorted_dst) {
    const int e = blockIdx.x * 256 + threadIdx.x;
    if (e >= NEDGES) return;
    const int pos = row_start[src[e]] + pos_in_row[e];
    sorted_dst[pos] = dst[e];
}

// ---------------- fused attention + aggregation (round-2, verified) ----------------
// 32 lanes per node. sub = lane&31 owns Wh/out channels [sub*8, sub*8+8).
// Label role: group g = sub>>3 handles edge g of each 4-edge batch; lane holds
// label channels [(sub&7)*4, +4). Dot via 3x shfl_xor in the 8-lane group,
// leakyrelu+exp, broadcast 4 w's, FMA the 4 gathered Wh rows.
__global__ __launch_bounds__(256) void k_aggregate(const unsigned short* __restrict__ Wh,
                                                   const float* __restrict__ label,
                                                   const int* __restrict__ row_start,
                                                   const int* __restrict__ sorted_dst,
                                                   float* __restrict__ out) {
    const int node = blockIdx.x * 8 + (threadIdx.x >> 5);
    if (node >= NNODES) return;
    const int lane = threadIdx.x & 63;
    const int sub  = lane & 31;
    const int base32 = lane & 32;
    const int g  = sub >> 3;
    const int c4 = (sub & 7) * 4;
    const int rs = row_start[node];
    const int re = (node == NNODES - 1) ? NEDGES : row_start[node + 1];
    const unsigned short* __restrict__ Whc = Wh + sub * 8;

    const float4 lsv = *(const float4*)&label[(size_t)node * 32 + c4];

    float acc[8] = {0.f, 0.f, 0.f, 0.f, 0.f, 0.f, 0.f, 0.f};
    float wsum = 0.f;
    int i = rs;
    for (; i + 4 <= re; i += 4) {
        const int d0 = sorted_dst[i + 0];
        const int d1 = sorted_dst[i + 1];
        const int d2 = sorted_dst[i + 2];
        const int d3 = sorted_dst[i + 3];
        const int dm = (g & 2) ? ((g & 1) ? d3 : d2) : ((g & 1) ? d1 : d0);
        const float4 ldv = *(const float4*)&label[(size_t)dm * 32 + c4];
        const u16x8 v0 = *(const u16x8*)&Whc[(size_t)d0 * 256];
        const u16x8 v1 = *(const u16x8*)&Whc[(size_t)d1 * 256];
        const u16x8 v2 = *(const u16x8*)&Whc[(size_t)d2 * 256];
        const u16x8 v3 = *(const u16x8*)&Whc[(size_t)d3 * 256];
        float p = lsv.x * ldv.x + lsv.y * ldv.y + lsv.z * ldv.z + lsv.w * ldv.w;
        p += __shfl_xor(p, 1);
        p += __shfl_xor(p, 2);
        p += __shfl_xor(p, 4);
        const float lr = fmaxf(p, ALPHA * p);
        const float wv = expf(lr);
        const float w0 = __shfl(wv, base32 + 0);
        const float w1 = __shfl(wv, base32 + 8);
        const float w2 = __shfl(wv, base32 + 16);
        const float w3 = __shfl(wv, base32 + 24);
        wsum += (w0 + w1) + (w2 + w3);
#pragma unroll
        for (int c = 0; c < 8; ++c) {
            acc[c] = fmaf(w0, bf2f(v0[c]), acc[c]);
            acc[c] = fmaf(w1, bf2f(v1[c]), acc[c]);
            acc[c] = fmaf(w2, bf2f(v2[c]), acc[c]);
            acc[c] = fmaf(w3, bf2f(v3[c]), acc[c]);
        }
    }
    for (; i < re; ++i) {
        const int d = sorted_dst[i];
        const float4 ldv = *(const float4*)&label[(size_t)d * 32 + c4];
        const u16x8 v = *(const u16x8*)&Whc[(size_t)d * 256];
        float p = lsv.x * ldv.x + lsv.y * ldv.y + lsv.z * ldv.z + lsv.w * ldv.w;
        p += __shfl_xor(p, 1);
        p += __shfl_xor(p, 2);
        p += __shfl_xor(p, 4);
        const float lr = fmaxf(p, ALPHA * p);
        const float w = expf(lr);
        wsum += w;
#pragma unroll
        for (int c = 0; c < 8; ++c) acc[c] = fmaf(w, bf2f(v[c]), acc[c]);
    }
    const float inv = 1.f / fmaxf(wsum, EPSV);
    float4 o0 = make_float4(acc[0] * inv, acc[1] * inv, acc[2] * inv, acc[3] * inv);
    float4 o1 = make_float4(acc[4] * inv, acc[5] * inv, acc[6] * inv, acc[7] * inv);
    float* orow = out + (size_t)node * 256 + sub * 8;
    *(float4*)(orow + 0) = o0;
    *(float4*)(orow + 4) = o1;
}

extern "C" void kernel_launch(void* const* d_in, const int* in_sizes, int n_in,
                              void* d_out, int out_size, void* d_ws, size_t ws_size,
                              hipStream_t stream) {
    const float* h     = (const float*)d_in[0];   // [N,256]
    const float* label = (const float*)d_in[1];   // [N,32]
    const float* W     = (const float*)d_in[2];   // [256,256]
    const int*   adj   = (const int*)d_in[3];     // [2,E]
    const int* src = adj;
    const int* dst = adj + NEDGES;
    float* out = (float*)d_out;

    // workspace layout (bytes, 16B-aligned offsets)
    char* ws = (char*)d_ws;
    unsigned short* Wh  = (unsigned short*)(ws + 0);          // N*256*2 = 51,200,000
    unsigned short* Wt  = (unsigned short*)(ws + 51200000);   // 256*256*2 = 131,072
    int* sorted_dst     = (int*)  (ws + 51400000);            // E*4 = 6,400,000
    int* pos_in_row     = (int*)  (ws + 57800000);            // E*4 = 6,400,000
    int* counts         = (int*)  (ws + 64200000);            // N*4
    int* row_start      = (int*)  (ws + 64600000);            // N*4
    int* blockSums      = (int*)  (ws + 65000000);            // 1024*4

    k_init<<<(NNODES + 255) / 256, 256, 0, stream>>>(W, Wt, counts);
    k_gemm<<<(NNODES + BM - 1) / BM, 256, 0, stream>>>(h, Wt, Wh, src, counts, pos_in_row);

    const int nb = (NNODES + 1023) / 1024;  // 98
    k_scan1<<<nb, 256, 0, stream>>>(counts, row_start, blockSums);
    k_scan2<<<1, 256, 0, stream>>>(blockSums, nb);
    k_scan3<<<(NNODES + 255) / 256, 256, 0, stream>>>(row_start, blockSums);

    k_scatter<<<(NEDGES + 255) / 256, 256, 0, stream>>>(src, dst, pos_in_row,
                                                        row_start, sorted_dst);
    k_aggregate<<<(NNODES + 7) / 8, 256, 0, stream>>>(Wh, label, row_start, sorted_dst, out);
}